// Round 2
// baseline (11551.275 us; speedup 1.0000x reference)
//
#include <hip/hip_runtime.h>

#define DEV __device__ __forceinline__

DEV float fast_rcp(float x) {
#if __has_builtin(__builtin_amdgcn_rcpf)
  return __builtin_amdgcn_rcpf(x);
#else
  return 1.0f / x;
#endif
}
DEV float sigm(float x) { return fast_rcp(1.0f + __expf(-x)); }
DEV float tanh_f(float x) {
  float e = __expf(-2.0f * fabsf(x));
  float t = 1.0f - 2.0f * e * fast_rcp(1.0f + e);
  return copysignf(t, x);
}
DEV float lrelu(float x) { return x > 0.0f ? x : 0.01f * x; }

DEV float wave_sum(float v) {
#pragma unroll
  for (int m = 32; m; m >>= 1) v += __shfl_xor(v, m);
  return v;
}
DEV float wave_max(float v) {
#pragma unroll
  for (int m = 32; m; m >>= 1) v = fmaxf(v, __shfl_xor(v, m));
  return v;
}
DEV float dot4(float4 w, float4 x, float acc) {
  acc = fmaf(w.x, x.x, acc);
  acc = fmaf(w.y, x.y, acc);
  acc = fmaf(w.z, x.z, acc);
  acc = fmaf(w.w, x.w, acc);
  return acc;
}

// ---------------------------------------------------------------------------
// Persistent-GRU encoder, R5: 8 waves/block (2 per SIMD) for latency overlap.
// lane = hidden unit j (owns all 3 gates of j -> no shuffles, no in-loop
// barriers; wave-private LDS state, program-order ds dependencies).
// LDS budget trick: Wih0 (6x3/lane) and the last 8 rows of Whh0 (8x3/lane)
// live in REGISTERS, so weights(LDS) = 56*192 + 128*192 floats = 141.8 KB,
// + state 8 waves * 5 seqs * 128 = 20 KB -> 161,792 B <= 160 KiB.
// Element access via named .x/.y/.z/.w only (no address-taken vector
// elements -> no scratch/mov bloat); all LDS refs rooted at the extern
// __shared__ array (guaranteed addrspace(3)).
// ---------------------------------------------------------------------------
constexpr int E_SPW = 5;
constexpr int E_WAVES = 8;
constexpr int E_W0H_ROWS = 56;                 // Whh0 k-rows 0..55 in LDS
constexpr int E_W0H_DW = E_W0H_ROWS * 192;     // 10752
constexpr int E_W1_DW = 128 * 192;             // 24576
constexpr int E_STATE_DW = E_WAVES * E_SPW * 128;  // 5120
constexpr int E_LDS = (E_W0H_DW + E_W1_DW + E_STATE_DW) * 4;  // 161792 B

__launch_bounds__(512, 2)
__global__ void gru2_enc(const float* __restrict__ x,      // [10240][60][6]
                         const float* __restrict__ w3e0,   // [70][192]
                         const float* __restrict__ w3e1,   // [128][192]
                         const float* __restrict__ bih0, const float* __restrict__ bhh0,
                         const float* __restrict__ bih1, const float* __restrict__ bhh1,
                         float* __restrict__ h_out) {      // [10240][64]
  extern __shared__ float lds[];
  const int tid = threadIdx.x;
  const int wave = tid >> 6;
  const int j = tid & 63;
  const int j3 = j * 3;
  const int W1O = E_W0H_DW;
  const int HB = E_W0H_DW + E_W1_DW + wave * (E_SPW * 128);

  // cooperative weight load into LDS (coalesced float4)
  {
    const float4* s0 = (const float4*)(w3e0 + 6 * 192);  // Whh0 rows 0..55
    for (int i = tid; i < E_W0H_DW / 4; i += 512) ((float4*)lds)[i] = s0[i];
    const float4* s1 = (const float4*)w3e1;
    for (int i = tid; i < E_W1_DW / 4; i += 512) ((float4*)(lds + W1O))[i] = s1[i];
  }
  // register weights: Wih0 (k=0..5) and Whh0 k=56..63 (rows 62..69 of w3e0)
  float wx0[6][3], wh_hi[8][3];
#pragma unroll
  for (int k = 0; k < 6; ++k)
#pragma unroll
    for (int g = 0; g < 3; ++g) wx0[k][g] = w3e0[k * 192 + j3 + g];
#pragma unroll
  for (int k = 0; k < 8; ++k)
#pragma unroll
    for (int g = 0; g < 3; ++g) wh_hi[k][g] = w3e0[(62 + k) * 192 + j3 + g];

  const float br0 = bih0[j] + bhh0[j];
  const float bz0 = bih0[64 + j] + bhh0[64 + j];
  const float bxn0 = bih0[128 + j];
  const float bhn0 = bhh0[128 + j];
  const float br1 = bih1[j] + bhh1[j];
  const float bz1 = bih1[64 + j] + bhh1[64 + j];
  const float bxn1 = bih1[128 + j];
  const float bhn1 = bhh1[128 + j];

  float h0r[E_SPW], h1r[E_SPW];
#pragma unroll
  for (int s = 0; s < E_SPW; ++s) {
    h0r[s] = 0.0f; h1r[s] = 0.0f;
    lds[HB + s * 128 + j] = 0.0f;
    lds[HB + s * 128 + 64 + j] = 0.0f;
  }
  __syncthreads();  // the only barrier

  const int seq0 = blockIdx.x * (E_WAVES * E_SPW) + wave * E_SPW;
  const float* xp = x + (size_t)seq0 * 360;

#define LOADX(dst, tt)                                             \
  _Pragma("unroll") for (int s = 0; s < E_SPW; ++s) {              \
    const float2* q = (const float2*)(xp + s * 360 + (tt) * 6);    \
    float2 a_ = q[0], b_ = q[1], c_ = q[2];                        \
    dst[s][0] = a_.x; dst[s][1] = a_.y; dst[s][2] = b_.x;          \
    dst[s][3] = b_.y; dst[s][4] = c_.x; dst[s][5] = c_.y;          \
  }

// one k-quad of a 64-wide dot: weights from LDS, h broadcast from LDS
#define DOT_QUAD(WB, WROW0, HOFF, AR, AZ, AN)                              \
  {                                                                        \
    float4 hv[E_SPW];                                                      \
    _Pragma("unroll") for (int s = 0; s < E_SPW; ++s)                      \
      hv[s] = *(const float4*)&lds[HB + s * 128 + (HOFF)];                 \
    _Pragma("unroll") for (int c = 0; c < 4; ++c) {                        \
      const float wr = lds[(WB) + ((WROW0) + c) * 192 + j3];               \
      const float wz = lds[(WB) + ((WROW0) + c) * 192 + j3 + 1];           \
      const float wn = lds[(WB) + ((WROW0) + c) * 192 + j3 + 2];           \
      _Pragma("unroll") for (int s = 0; s < E_SPW; ++s) {                  \
        const float hc = (c == 0) ? hv[s].x                                \
                        : (c == 1) ? hv[s].y                               \
                        : (c == 2) ? hv[s].z : hv[s].w;                    \
        AR[s] = fmaf(wr, hc, AR[s]);                                       \
        AZ[s] = fmaf(wz, hc, AZ[s]);                                       \
        AN[s] = fmaf(wn, hc, AN[s]);                                       \
      }                                                                    \
    }                                                                      \
  }

  float xv[E_SPW][6];
  LOADX(xv, 0);

  for (int t = 0; t < 60; ++t) {
    float xn[E_SPW][6];
    if (t + 1 < 60) LOADX(xn, t + 1);

    float ar[E_SPW], az[E_SPW], anx[E_SPW], anh[E_SPW];
#pragma unroll
    for (int s = 0; s < E_SPW; ++s) { ar[s] = 0.f; az[s] = 0.f; anx[s] = 0.f; anh[s] = 0.f; }

    // ---- layer0 x-part from register weights
#pragma unroll
    for (int k = 0; k < 6; ++k)
#pragma unroll
      for (int s = 0; s < E_SPW; ++s) {
        ar[s] = fmaf(wx0[k][0], xv[s][k], ar[s]);
        az[s] = fmaf(wx0[k][1], xv[s][k], az[s]);
        anx[s] = fmaf(wx0[k][2], xv[s][k], anx[s]);
      }
    // ---- layer0 h-part: k = 0..55 from LDS weights
#pragma unroll
    for (int kq = 0; kq < 14; ++kq) DOT_QUAD(0, kq * 4, kq * 4, ar, az, anh);
    // k = 56..63 from register weights
#pragma unroll
    for (int kq = 14; kq < 16; ++kq) {
      float4 hv[E_SPW];
#pragma unroll
      for (int s = 0; s < E_SPW; ++s)
        hv[s] = *(const float4*)&lds[HB + s * 128 + kq * 4];
#pragma unroll
      for (int c = 0; c < 4; ++c) {
        const int kk = kq * 4 + c - 56;
        const float wr = wh_hi[kk][0], wz = wh_hi[kk][1], wn = wh_hi[kk][2];
#pragma unroll
        for (int s = 0; s < E_SPW; ++s) {
          const float hc = (c == 0) ? hv[s].x
                          : (c == 1) ? hv[s].y
                          : (c == 2) ? hv[s].z : hv[s].w;
          ar[s] = fmaf(wr, hc, ar[s]);
          az[s] = fmaf(wz, hc, az[s]);
          anh[s] = fmaf(wn, hc, anh[s]);
        }
      }
    }
    // ---- layer0 epilogue
#pragma unroll
    for (int s = 0; s < E_SPW; ++s) {
      float r = sigm(ar[s] + br0);
      float z = sigm(az[s] + bz0);
      float n = tanh_f(anx[s] + bxn0 + r * (anh[s] + bhn0));
      float h0 = (1.0f - z) * n + z * h0r[s];
      h0r[s] = h0;
      lds[HB + s * 128 + j] = h0;  // wave-private; ordered by lgkmcnt
    }

#pragma unroll
    for (int s = 0; s < E_SPW; ++s) { ar[s] = 0.f; az[s] = 0.f; anx[s] = 0.f; anh[s] = 0.f; }
    // ---- layer1 x-part over fresh h0 (W1 rows 0..63)
#pragma unroll
    for (int kq = 0; kq < 16; ++kq) DOT_QUAD(W1O, kq * 4, kq * 4, ar, az, anx);
    // ---- layer1 h-part over h1_old (W1 rows 64..127)
#pragma unroll
    for (int kq = 0; kq < 16; ++kq) DOT_QUAD(W1O, 64 + kq * 4, 64 + kq * 4, ar, az, anh);
    // ---- layer1 epilogue
#pragma unroll
    for (int s = 0; s < E_SPW; ++s) {
      float r = sigm(ar[s] + br1);
      float z = sigm(az[s] + bz1);
      float n = tanh_f(anx[s] + bxn1 + r * (anh[s] + bhn1));
      float h1 = (1.0f - z) * n + z * h1r[s];
      h1r[s] = h1;
      lds[HB + s * 128 + 64 + j] = h1;
    }

#pragma unroll
    for (int s = 0; s < E_SPW; ++s)
#pragma unroll
      for (int i = 0; i < 6; ++i) xv[s][i] = xn[s][i];
  }

#pragma unroll
  for (int s = 0; s < E_SPW; ++s)
    h_out[(size_t)(seq0 + s) * 64 + j] = h1r[s];
#undef DOT_QUAD
#undef LOADX
}

// ---------------------------------------------------------------------------
// Single-layer GRU for the ALSTM (I = 64). 8 waves/block (2/SIMD), 1 seq per
// wave -> grid 64 blocks, latency-spread. Same wave-private structure.
// ---------------------------------------------------------------------------
constexpr int A_W_DW = 128 * 192;  // 24576
constexpr int A_WAVES = 8;
constexpr int A_LDS = (A_W_DW + A_WAVES * 128) * 4;  // 102400 B

__launch_bounds__(512, 2)
__global__ void gru1(const float* __restrict__ xin,  // [N][T][64]
                     const float* __restrict__ w3,   // [128][192]
                     const float* __restrict__ bih, const float* __restrict__ bhh,
                     int T,
                     float* __restrict__ rout) {     // [N][T][64]
  extern __shared__ float lds[];
  const int tid = threadIdx.x;
  const int wave = tid >> 6;
  const int j = tid & 63;
  const int j3 = j * 3;
  const int XB = A_W_DW + wave * 128;  // [0..63]=x_t, [64..127]=h

  {
    const float4* sp = (const float4*)w3;
    for (int i = tid; i < A_W_DW / 4; i += 512) ((float4*)lds)[i] = sp[i];
  }
  const float br = bih[j] + bhh[j];
  const float bz = bih[64 + j] + bhh[64 + j];
  const float bxn = bih[128 + j];
  const float bhn = bhh[128 + j];

  float hr = 0.0f;
  lds[XB + 64 + j] = 0.0f;
  __syncthreads();

  const int seq = blockIdx.x * A_WAVES + wave;
  const float* xs = xin + (size_t)seq * T * 64;

#define A_QUAD(WROW0, HOFF, AN)                                            \
  {                                                                        \
    float4 hv = *(const float4*)&lds[XB + (HOFF)];                         \
    _Pragma("unroll") for (int c = 0; c < 4; ++c) {                        \
      const float wr = lds[((WROW0) + c) * 192 + j3];                      \
      const float wz = lds[((WROW0) + c) * 192 + j3 + 1];                  \
      const float wn = lds[((WROW0) + c) * 192 + j3 + 2];                  \
      const float hc = (c == 0) ? hv.x : (c == 1) ? hv.y                   \
                      : (c == 2) ? hv.z : hv.w;                            \
      ar = fmaf(wr, hc, ar);                                               \
      az = fmaf(wz, hc, az);                                               \
      AN = fmaf(wn, hc, AN);                                               \
    }                                                                      \
  }

  float xcur = xs[j];  // t = 0
  for (int t = 0; t < T; ++t) {
    float xnext = (t + 1 < T) ? xs[(size_t)(t + 1) * 64 + j] : 0.0f;
    lds[XB + j] = xcur;  // wave-private; ordered by lgkmcnt

    float ar = 0.f, az = 0.f, anx = 0.f, anh = 0.f;
#pragma unroll
    for (int kq = 0; kq < 16; ++kq) A_QUAD(kq * 4, kq * 4, anx);        // input
#pragma unroll
    for (int kq = 0; kq < 16; ++kq) A_QUAD(64 + kq * 4, 64 + kq * 4, anh);  // rec

    float r = sigm(ar + br);
    float z = sigm(az + bz);
    float n = tanh_f(anx + bxn + r * (anh + bhn));
    float h = (1.0f - z) * n + z * hr;
    hr = h;
    lds[XB + 64 + j] = h;
    rout[((size_t)seq * T + t) * 64 + j] = h;
    xcur = xnext;
  }
#undef A_QUAD
}

// ---------------------------------------------------------------------------
// Weight interleave prep: W3[k][j*3+g] = (k<I ? Wih[g*64+j][k] : Whh[g*64+j][k-I])
// ---------------------------------------------------------------------------
__global__ void w3_prep(const float* __restrict__ Wih0, const float* __restrict__ Whh0,
                        const float* __restrict__ Wih1, const float* __restrict__ Whh1,
                        const float* __restrict__ aWih0, const float* __restrict__ aWhh0,
                        const float* __restrict__ aWih1, const float* __restrict__ aWhh1,
                        float* __restrict__ d_e0, float* __restrict__ d_e1,
                        float* __restrict__ d_a0, float* __restrict__ d_a1) {
  const int sec = blockIdx.x >> 3;
  const int bi = blockIdx.x & 7;
  const float* Wih; const float* Whh; float* dst; int I;
  if (sec == 0)      { Wih = Wih0;  Whh = Whh0;  dst = d_e0; I = 6; }
  else if (sec == 1) { Wih = Wih1;  Whh = Whh1;  dst = d_e1; I = 64; }
  else if (sec == 2) { Wih = aWih0; Whh = aWhh0; dst = d_a0; I = 64; }
  else               { Wih = aWih1; Whh = aWhh1; dst = d_a1; I = 64; }
  const int tot = (I + 64) * 192;
  for (int idx = bi * blockDim.x + threadIdx.x; idx < tot; idx += 8 * blockDim.x) {
    const int k = idx / 192;
    const int rem = idx - k * 192;
    const int j = rem / 3;
    const int g = rem - j * 3;
    const float v = (k < I) ? Wih[(g * 64 + j) * I + k] : Whh[(g * 64 + j) * 64 + (k - I)];
    dst[idx] = v;
  }
}

// ---------------------------------------------------------------------------
// GAT algebraic prep
// ---------------------------------------------------------------------------
__global__ void gat_prep(const float* __restrict__ tW, const float* __restrict__ tb,
                         const float* __restrict__ a, float* __restrict__ vbuf) {
  const int d = threadIdx.x;  // 64 threads
  float vd = 0.0f, vs = 0.0f;
  for (int e = 0; e < 64; ++e) {
    float w = tW[e * 64 + d];
    vd = fmaf(w, a[e], vd);
    vs = fmaf(w, a[64 + e], vs);
  }
  vbuf[d] = vd;
  vbuf[64 + d] = vs;
  if (d == 0) {
    float cd = 0.0f, cs = 0.0f;
    for (int e = 0; e < 64; ++e) {
      cd = fmaf(tb[e], a[e], cd);
      cs = fmaf(tb[e], a[64 + e], cs);
    }
    vbuf[128] = cd;
    vbuf[129] = cs;
  }
}

__global__ void gat_svals(const float* __restrict__ h_enc, const float* __restrict__ vbuf,
                          float* __restrict__ s_src, float* __restrict__ s_dst) {
  const int wave = (blockIdx.x * blockDim.x + threadIdx.x) >> 6;
  const int lane = threadIdx.x & 63;
  float h = h_enc[(size_t)wave * 64 + lane];
  float pd = h * vbuf[lane];
  float ps = h * vbuf[64 + lane];
  pd = wave_sum(pd);
  ps = wave_sum(ps);
  if (lane == 0) {
    s_dst[wave] = pd + vbuf[128];
    s_src[wave] = ps + vbuf[129];
  }
}

// ---------------------------------------------------------------------------
// Dense all-pairs attention per group k (m=512)
// ---------------------------------------------------------------------------
__launch_bounds__(256)
__global__ void gat_attn(const float* __restrict__ h_enc,
                         const float* __restrict__ s_src,
                         const float* __restrict__ s_dst,
                         float* __restrict__ hout) {
  const int k = blockIdx.x >> 7;
  const int tile = blockIdx.x & 127;
  const int wv = threadIdx.x >> 6;
  const int lane = threadIdx.x & 63;
  const int i = tile * 4 + wv;
  __shared__ float sdbuf[512];
  __shared__ __align__(16) float pbuf[4][512];

  for (int u = threadIdx.x; u < 512; u += 256) sdbuf[u] = s_dst[k * 512 + u];
  __syncthreads();

  const float si = s_src[k * 512 + i];
  float ev[8];
  float mx = -1e30f;
#pragma unroll
  for (int u = 0; u < 8; ++u) {
    ev[u] = lrelu(si + sdbuf[lane + u * 64]);
    mx = fmaxf(mx, ev[u]);
  }
  mx = wave_max(mx);
  float lsum = 0.0f;
#pragma unroll
  for (int u = 0; u < 8; ++u) {
    float p = __expf(ev[u] - mx);
    pbuf[wv][lane + u * 64] = p;
    lsum += p;
  }
  lsum = wave_sum(lsum);
  const float inv = fast_rcp(lsum);

  const float* hk = h_enc + (size_t)k * 512 * 64;
  const float4* pv = (const float4*)pbuf[wv];
  float acc0 = 0.0f, acc1 = 0.0f;
#pragma unroll 2
  for (int jj = 0; jj < 128; ++jj) {
    float4 p = pv[jj];
    const float* hp = hk + (size_t)(jj * 4) * 64 + lane;
    acc0 = fmaf(p.x, hp[0], acc0);
    acc1 = fmaf(p.y, hp[64], acc1);
    acc0 = fmaf(p.z, hp[128], acc0);
    acc1 = fmaf(p.w, hp[192], acc1);
  }
  hout[((size_t)k * 512 + i) * 64 + lane] =
      (acc0 + acc1) * inv + hk[(size_t)i * 64 + lane];
}

// ---------------------------------------------------------------------------
// Post-GAT transform + pred head + ALSTM input transform
// ---------------------------------------------------------------------------
__launch_bounds__(256)
__global__ void gat_out(const float* __restrict__ hin,
                        const float* __restrict__ fcW, const float* __restrict__ fcb,
                        const float* __restrict__ fcoW, const float* __restrict__ fcob,
                        const float* __restrict__ alinW, const float* __restrict__ alinb,
                        float* __restrict__ zout, float* __restrict__ pred) {
  const int wv = threadIdx.x >> 6;
  const int lane = threadIdx.x & 63;
  const int n = blockIdx.x * 4 + wv;  // [0,10240)
  const int k = n >> 9;
  const int i = n & 511;
  __shared__ __align__(16) float rbuf[4][64];
  __shared__ __align__(16) float rbuf2[4][64];

  float4 fw[16], aw[16];
  {
    const float4* p1 = (const float4*)(fcW + lane * 64);
    const float4* p2 = (const float4*)(alinW + lane * 64);
#pragma unroll
    for (int kk = 0; kk < 16; ++kk) fw[kk] = p1[kk];
#pragma unroll
    for (int kk = 0; kk < 16; ++kk) aw[kk] = p2[kk];
  }

  rbuf[wv][lane] = hin[(size_t)n * 64 + lane];
  float h2 = fcb[lane];
  const float4* rv = (const float4*)rbuf[wv];
#pragma unroll
  for (int kk = 0; kk < 16; ++kk) h2 = dot4(fw[kk], rv[kk], h2);

  if (k == 19) {
    float pv = lrelu(h2) * fcoW[lane];
    pv = wave_sum(pv);
    if (lane == 0) pred[i] = pv + fcob[0];
  }

  rbuf2[wv][lane] = h2;
  float zz = alinb[lane];
  const float4* rv2 = (const float4*)rbuf2[wv];
#pragma unroll
  for (int kk = 0; kk < 16; ++kk) zz = dot4(aw[kk], rv2[kk], zz);
  zout[((size_t)i * 20 + k) * 64 + lane] = tanh_f(zz);
}

// ---------------------------------------------------------------------------
// ALSTM attention head
// ---------------------------------------------------------------------------
__launch_bounds__(256)
__global__ void alstm_head(const float* __restrict__ r1,  // [512][20][64]
                           const float* __restrict__ W1,  // [32][64]
                           const float* __restrict__ b1,  // [32]
                           const float* __restrict__ W2,  // [32]
                           const float* __restrict__ Wo,  // [128]
                           const float* __restrict__ bo,  // [1]
                           float* __restrict__ alstm_out) {
  const int wv = threadIdx.x >> 6;
  const int lane = threadIdx.x & 63;
  const int i = blockIdx.x * 4 + wv;  // [0,512)
  const int e = lane & 31;
  __shared__ __align__(16) float rbuf[4][64];
  __shared__ float scb[4][20];

  float4 w1r[16];
  {
    const float4* p = (const float4*)(W1 + e * 64);
#pragma unroll
    for (int kk = 0; kk < 16; ++kk) w1r[kk] = p[kk];
  }
  const float b1e = b1[e];
  const float w2e = W2[e];

  for (int k = 0; k < 20; ++k) {
    rbuf[wv][lane] = r1[((size_t)i * 20 + k) * 64 + lane];
    float u = b1e;
    const float4* rp = (const float4*)rbuf[wv];
#pragma unroll
    for (int kk = 0; kk < 16; ++kk) u = dot4(w1r[kk], rp[kk], u);
    u = tanh_f(u) * w2e;
#pragma unroll
    for (int m = 16; m; m >>= 1) u += __shfl_xor(u, m);
    if (lane == 0) scb[wv][k] = u;
  }

  float mx = -1e30f;
#pragma unroll
  for (int k = 0; k < 20; ++k) mx = fmaxf(mx, scb[wv][k]);
  float p[20];
  float l = 0.0f;
#pragma unroll
  for (int k = 0; k < 20; ++k) {
    p[k] = __expf(scb[wv][k] - mx);
    l += p[k];
  }
  const float inv = fast_rcp(l);

  float oa = 0.0f, rlast = 0.0f;
#pragma unroll
  for (int k = 0; k < 20; ++k) {
    float rv = r1[((size_t)i * 20 + k) * 64 + lane];
    oa = fmaf(p[k], rv, oa);
    if (k == 19) rlast = rv;
  }
  oa *= inv;
  float v = fmaf(Wo[lane], rlast, Wo[64 + lane] * oa);
  v = wave_sum(v);
  if (lane == 0) alstm_out[i] = v + bo[0];
}

// ---------------------------------------------------------------------------
extern "C" void kernel_launch(void* const* d_in, const int* in_sizes, int n_in,
                              void* d_out, int out_size, void* d_ws, size_t ws_size,
                              hipStream_t stream) {
  const float* x      = (const float*)d_in[0];
  const float* Wih0   = (const float*)d_in[1];
  const float* Whh0   = (const float*)d_in[2];
  const float* bih0   = (const float*)d_in[3];
  const float* bhh0   = (const float*)d_in[4];
  const float* Wih1   = (const float*)d_in[5];
  const float* Whh1   = (const float*)d_in[6];
  const float* bih1   = (const float*)d_in[7];
  const float* bhh1   = (const float*)d_in[8];
  const float* transW = (const float*)d_in[9];
  const float* transb = (const float*)d_in[10];
  const float* a_vec  = (const float*)d_in[11];
  const float* fcW    = (const float*)d_in[12];
  const float* fcb    = (const float*)d_in[13];
  const float* fcoW   = (const float*)d_in[14];
  const float* fcob   = (const float*)d_in[15];
  const float* alinW  = (const float*)d_in[16];
  const float* alinb  = (const float*)d_in[17];
  const float* aWih0  = (const float*)d_in[18];
  const float* aWhh0  = (const float*)d_in[19];
  const float* abih0  = (const float*)d_in[20];
  const float* abhh0  = (const float*)d_in[21];
  const float* aWih1  = (const float*)d_in[22];
  const float* aWhh1  = (const float*)d_in[23];
  const float* abih1  = (const float*)d_in[24];
  const float* abhh1  = (const float*)d_in[25];
  const float* att1W  = (const float*)d_in[26];
  const float* att1b  = (const float*)d_in[27];
  const float* att2W  = (const float*)d_in[28];
  const float* aloutW = (const float*)d_in[29];
  const float* aloutb = (const float*)d_in[30];

  float* out = (float*)d_out;  // [0:512) alstm_out, [512:1024) pred

  float* W = (float*)d_ws;
  float* h_enc = W; W += 10240 * 64;      // reused as r0 (steps 7-8)
  float* vbuf  = W; W += 256;
  float* s_src = W; W += 10240;
  float* s_dst = W; W += 10240;
  float* hout  = W; W += 10240 * 64;
  float* zbuf  = W; W += 512 * 20 * 64;
  float* r1    = W; W += 512 * 20 * 64;
  float* w3a0  = W; W += 24576;
  float* w3a1  = W; W += 24576;
  // time-disjoint aliases: w3e* in zbuf region (consumed at step 2, zbuf
  // written at step 6); r0 in h_enc region (h_enc last read at step 5).
  float* w3e0 = zbuf;
  float* w3e1 = zbuf + 70 * 192;

  static bool attr_done = false;
  if (!attr_done) {
    hipFuncSetAttribute((const void*)gru2_enc,
                        hipFuncAttributeMaxDynamicSharedMemorySize, E_LDS);
    hipFuncSetAttribute((const void*)gru1,
                        hipFuncAttributeMaxDynamicSharedMemorySize, A_LDS);
    attr_done = true;
  }

  // 1) weight interleave prep (all 4 GRU layers)
  w3_prep<<<32, 256, 0, stream>>>(Wih0, Whh0, Wih1, Whh1, aWih0, aWhh0,
                                  aWih1, aWhh1, w3e0, w3e1, w3a0, w3a1);
  // 2) fused 2-layer persistent GRU encoder (256 blocks = 1 balanced round)
  gru2_enc<<<256, 512, E_LDS, stream>>>(x, w3e0, w3e1, bih0, bhh0, bih1,
                                        bhh1, h_enc);
  // 3) GAT score-vector prep
  gat_prep<<<1, 64, 0, stream>>>(transW, transb, a_vec, vbuf);
  // 4) per-row s_src/s_dst
  gat_svals<<<2560, 256, 0, stream>>>(h_enc, vbuf, s_src, s_dst);
  // 5) dense attention + residual
  gat_attn<<<2560, 256, 0, stream>>>(h_enc, s_src, s_dst, hout);
  // 6) fc + pred head + ALSTM input transform (z in [i][k][64])
  gat_out<<<2560, 256, 0, stream>>>(hout, fcW, fcb, fcoW, fcob, alinW, alinb,
                                    zbuf, out + 512);
  // 7) ALSTM GRU layer 0: z -> r0 (reuses h_enc storage)
  gru1<<<64, 512, A_LDS, stream>>>(zbuf, w3a0, abih0, abhh0, 20, h_enc);
  // 8) ALSTM GRU layer 1: r0 -> r1
  gru1<<<64, 512, A_LDS, stream>>>(h_enc, w3a1, abih1, abhh1, 20, r1);
  // 9) ALSTM attention head -> alstm_out
  alstm_head<<<128, 256, 0, stream>>>(r1, att1W, att1b, att2W, aloutW, aloutb,
                                      out);
}

// Round 3
// 4412.962 us; speedup vs baseline: 2.6176x; 2.6176x over previous
//
#include <hip/hip_runtime.h>

#define DEV __device__ __forceinline__

DEV float fast_rcp(float x) {
#if __has_builtin(__builtin_amdgcn_rcpf)
  return __builtin_amdgcn_rcpf(x);
#else
  return 1.0f / x;
#endif
}
DEV float sigm(float x) { return fast_rcp(1.0f + __expf(-x)); }
DEV float tanh_f(float x) {
  float e = __expf(-2.0f * fabsf(x));
  float t = 1.0f - 2.0f * e * fast_rcp(1.0f + e);
  return copysignf(t, x);
}
DEV float lrelu(float x) { return x > 0.0f ? x : 0.01f * x; }

DEV float wave_sum(float v) {
#pragma unroll
  for (int m = 32; m; m >>= 1) v += __shfl_xor(v, m);
  return v;
}
DEV float wave_max(float v) {
#pragma unroll
  for (int m = 32; m; m >>= 1) v = fmaxf(v, __shfl_xor(v, m));
  return v;
}
DEV float dot4(float4 w, float4 x, float acc) {
  acc = fmaf(w.x, x.x, acc);
  acc = fmaf(w.y, x.y, acc);
  acc = fmaf(w.z, x.z, acc);
  acc = fmaf(w.w, x.w, acc);
  return acc;
}

// ---------------------------------------------------------------------------
// Persistent-GRU encoder, R6. Lessons: R5(512thr,SPW5,cap128) SPILLED (18.7GB
// scratch HBM, VALUBusy 6%). R6 = 10 waves x SPW=4 (640 thr) -> 40 seq/block
// -> 256 blocks = ONE balanced round; cap via __launch_bounds__(640,3) ->
// VGPR<=170, budget ~138 (42 regwt + 16 acc + 24 xv + 8 h + 16 hv + ~30 misc)
// -> no spill. No x prefetch: x loads issue at step top, h-part (pure
// LDS/VALU) runs first, x consumed after -> global latency hidden.
// lane = hidden unit j (owns all 3 gates -> no shuffles, no in-loop
// barriers; wave-private LDS state, program-order ds dependencies).
// Weights LDS-resident except Wih0(6 rows) + Whh0 k=56..63 (8 rows) in regs:
// LDS = 56*192 + 128*192 + 10*4*128 = 40448 dw = 161,792 B <= 160 KiB.
// Weight reads stride-3 dwords -> gcd(3,32)=1 -> 2 lanes/bank = free.
// ---------------------------------------------------------------------------
constexpr int E_SPW = 4;
constexpr int E_WAVES = 10;
constexpr int E_W0H_DW = 56 * 192;             // Whh0 k-rows 0..55 in LDS
constexpr int E_W1_DW = 128 * 192;             // 24576
constexpr int E_STATE_DW = E_WAVES * E_SPW * 128;  // 5120
constexpr int E_LDS = (E_W0H_DW + E_W1_DW + E_STATE_DW) * 4;  // 161792 B

__launch_bounds__(640, 3)
__global__ void gru2_enc(const float* __restrict__ x,      // [10240][60][6]
                         const float* __restrict__ w3e0,   // [70][192]
                         const float* __restrict__ w3e1,   // [128][192]
                         const float* __restrict__ bih0, const float* __restrict__ bhh0,
                         const float* __restrict__ bih1, const float* __restrict__ bhh1,
                         float* __restrict__ h_out) {      // [10240][64]
  extern __shared__ float lds[];
  const int tid = threadIdx.x;
  const int wave = tid >> 6;
  const int j = tid & 63;
  const int j3 = j * 3;
  const int W1O = E_W0H_DW;
  const int HB = E_W0H_DW + E_W1_DW + wave * (E_SPW * 128);

  // cooperative weight load into LDS (coalesced float4)
  {
    const float4* s0 = (const float4*)(w3e0 + 6 * 192);  // Whh0 rows 0..55
    for (int i = tid; i < E_W0H_DW / 4; i += 640) ((float4*)lds)[i] = s0[i];
    const float4* s1 = (const float4*)w3e1;
    for (int i = tid; i < E_W1_DW / 4; i += 640) ((float4*)(lds + W1O))[i] = s1[i];
  }
  // register weights: Wih0 (k=0..5) and Whh0 k=56..63 (rows 62..69 of w3e0)
  float wx0[6][3], wh_hi[8][3];
#pragma unroll
  for (int k = 0; k < 6; ++k)
#pragma unroll
    for (int g = 0; g < 3; ++g) wx0[k][g] = w3e0[k * 192 + j3 + g];
#pragma unroll
  for (int k = 0; k < 8; ++k)
#pragma unroll
    for (int g = 0; g < 3; ++g) wh_hi[k][g] = w3e0[(62 + k) * 192 + j3 + g];

  const float br0 = bih0[j] + bhh0[j];
  const float bz0 = bih0[64 + j] + bhh0[64 + j];
  const float bxn0 = bih0[128 + j];
  const float bhn0 = bhh0[128 + j];
  const float br1 = bih1[j] + bhh1[j];
  const float bz1 = bih1[64 + j] + bhh1[64 + j];
  const float bxn1 = bih1[128 + j];
  const float bhn1 = bhh1[128 + j];

  float h0r[E_SPW], h1r[E_SPW];
#pragma unroll
  for (int s = 0; s < E_SPW; ++s) {
    h0r[s] = 0.0f; h1r[s] = 0.0f;
    lds[HB + s * 128 + j] = 0.0f;
    lds[HB + s * 128 + 64 + j] = 0.0f;
  }
  __syncthreads();  // the only barrier

  const int seq0 = blockIdx.x * (E_WAVES * E_SPW) + wave * E_SPW;
  const float* xp = x + (size_t)seq0 * 360;

// one k-quad of a 64-wide dot: weights from LDS, h broadcast from LDS
#define DOT_QUAD(WB, WROW0, HOFF, AR, AZ, AN)                              \
  {                                                                        \
    float4 hv[E_SPW];                                                      \
    _Pragma("unroll") for (int s = 0; s < E_SPW; ++s)                      \
      hv[s] = *(const float4*)&lds[HB + s * 128 + (HOFF)];                 \
    _Pragma("unroll") for (int c = 0; c < 4; ++c) {                        \
      const float wr = lds[(WB) + ((WROW0) + c) * 192 + j3];               \
      const float wz = lds[(WB) + ((WROW0) + c) * 192 + j3 + 1];           \
      const float wn = lds[(WB) + ((WROW0) + c) * 192 + j3 + 2];           \
      _Pragma("unroll") for (int s = 0; s < E_SPW; ++s) {                  \
        const float hc = (c == 0) ? hv[s].x                                \
                        : (c == 1) ? hv[s].y                               \
                        : (c == 2) ? hv[s].z : hv[s].w;                    \
        AR[s] = fmaf(wr, hc, AR[s]);                                       \
        AZ[s] = fmaf(wz, hc, AZ[s]);                                       \
        AN[s] = fmaf(wn, hc, AN[s]);                                       \
      }                                                                    \
    }                                                                      \
  }

  for (int t = 0; t < 60; ++t) {
    // issue x[t] loads first (3x float2 per seq); consumed only after the
    // h-part below -> ~3k cycles of latency hiding, no prefetch registers.
    float xv[E_SPW][6];
#pragma unroll
    for (int s = 0; s < E_SPW; ++s) {
      const float2* q = (const float2*)(xp + s * 360 + t * 6);
      float2 a_ = q[0], b_ = q[1], c_ = q[2];
      xv[s][0] = a_.x; xv[s][1] = a_.y; xv[s][2] = b_.x;
      xv[s][3] = b_.y; xv[s][4] = c_.x; xv[s][5] = c_.y;
    }

    float ar[E_SPW], az[E_SPW], anx[E_SPW], anh[E_SPW];
#pragma unroll
    for (int s = 0; s < E_SPW; ++s) { ar[s] = 0.f; az[s] = 0.f; anx[s] = 0.f; anh[s] = 0.f; }

    // ---- layer0 h-part first (pure LDS/VALU): k = 0..55 from LDS weights
#pragma unroll
    for (int kq = 0; kq < 14; ++kq) DOT_QUAD(0, kq * 4, kq * 4, ar, az, anh);
    // k = 56..63 from register weights
#pragma unroll
    for (int kq = 14; kq < 16; ++kq) {
      float4 hv[E_SPW];
#pragma unroll
      for (int s = 0; s < E_SPW; ++s)
        hv[s] = *(const float4*)&lds[HB + s * 128 + kq * 4];
#pragma unroll
      for (int c = 0; c < 4; ++c) {
        const int kk = kq * 4 + c - 56;
        const float wr = wh_hi[kk][0], wz = wh_hi[kk][1], wn = wh_hi[kk][2];
#pragma unroll
        for (int s = 0; s < E_SPW; ++s) {
          const float hc = (c == 0) ? hv[s].x
                          : (c == 1) ? hv[s].y
                          : (c == 2) ? hv[s].z : hv[s].w;
          ar[s] = fmaf(wr, hc, ar[s]);
          az[s] = fmaf(wz, hc, az[s]);
          anh[s] = fmaf(wn, hc, anh[s]);
        }
      }
    }
    // ---- layer0 x-part from register weights (x loads have landed by now)
#pragma unroll
    for (int k = 0; k < 6; ++k)
#pragma unroll
      for (int s = 0; s < E_SPW; ++s) {
        ar[s] = fmaf(wx0[k][0], xv[s][k], ar[s]);
        az[s] = fmaf(wx0[k][1], xv[s][k], az[s]);
        anx[s] = fmaf(wx0[k][2], xv[s][k], anx[s]);
      }
    // ---- layer0 epilogue
#pragma unroll
    for (int s = 0; s < E_SPW; ++s) {
      float r = sigm(ar[s] + br0);
      float z = sigm(az[s] + bz0);
      float n = tanh_f(anx[s] + bxn0 + r * (anh[s] + bhn0));
      float h0 = (1.0f - z) * n + z * h0r[s];
      h0r[s] = h0;
      lds[HB + s * 128 + j] = h0;  // wave-private; ordered by lgkmcnt
    }

#pragma unroll
    for (int s = 0; s < E_SPW; ++s) { ar[s] = 0.f; az[s] = 0.f; anx[s] = 0.f; anh[s] = 0.f; }
    // ---- layer1 x-part over fresh h0 (W1 rows 0..63)
#pragma unroll
    for (int kq = 0; kq < 16; ++kq) DOT_QUAD(W1O, kq * 4, kq * 4, ar, az, anx);
    // ---- layer1 h-part over h1_old (W1 rows 64..127)
#pragma unroll
    for (int kq = 0; kq < 16; ++kq) DOT_QUAD(W1O, 64 + kq * 4, 64 + kq * 4, ar, az, anh);
    // ---- layer1 epilogue
#pragma unroll
    for (int s = 0; s < E_SPW; ++s) {
      float r = sigm(ar[s] + br1);
      float z = sigm(az[s] + bz1);
      float n = tanh_f(anx[s] + bxn1 + r * (anh[s] + bhn1));
      float h1 = (1.0f - z) * n + z * h1r[s];
      h1r[s] = h1;
      lds[HB + s * 128 + 64 + j] = h1;
    }
  }

#pragma unroll
  for (int s = 0; s < E_SPW; ++s)
    h_out[(size_t)(seq0 + s) * 64 + j] = h1r[s];
#undef DOT_QUAD
}

// ---------------------------------------------------------------------------
// Single-layer GRU for the ALSTM (I = 64). 8 waves/block (2/SIMD), 1 seq per
// wave -> grid 64 blocks, latency-spread. Same wave-private structure.
// ---------------------------------------------------------------------------
constexpr int A_W_DW = 128 * 192;  // 24576
constexpr int A_WAVES = 8;
constexpr int A_LDS = (A_W_DW + A_WAVES * 128) * 4;  // 102400 B

__launch_bounds__(512, 2)
__global__ void gru1(const float* __restrict__ xin,  // [N][T][64]
                     const float* __restrict__ w3,   // [128][192]
                     const float* __restrict__ bih, const float* __restrict__ bhh,
                     int T,
                     float* __restrict__ rout) {     // [N][T][64]
  extern __shared__ float lds[];
  const int tid = threadIdx.x;
  const int wave = tid >> 6;
  const int j = tid & 63;
  const int j3 = j * 3;
  const int XB = A_W_DW + wave * 128;  // [0..63]=x_t, [64..127]=h

  {
    const float4* sp = (const float4*)w3;
    for (int i = tid; i < A_W_DW / 4; i += 512) ((float4*)lds)[i] = sp[i];
  }
  const float br = bih[j] + bhh[j];
  const float bz = bih[64 + j] + bhh[64 + j];
  const float bxn = bih[128 + j];
  const float bhn = bhh[128 + j];

  float hr = 0.0f;
  lds[XB + 64 + j] = 0.0f;
  __syncthreads();

  const int seq = blockIdx.x * A_WAVES + wave;
  const float* xs = xin + (size_t)seq * T * 64;

#define A_QUAD(WROW0, HOFF, AN)                                            \
  {                                                                        \
    float4 hv = *(const float4*)&lds[XB + (HOFF)];                         \
    _Pragma("unroll") for (int c = 0; c < 4; ++c) {                        \
      const float wr = lds[((WROW0) + c) * 192 + j3];                      \
      const float wz = lds[((WROW0) + c) * 192 + j3 + 1];                  \
      const float wn = lds[((WROW0) + c) * 192 + j3 + 2];                  \
      const float hc = (c == 0) ? hv.x : (c == 1) ? hv.y                   \
                      : (c == 2) ? hv.z : hv.w;                            \
      ar = fmaf(wr, hc, ar);                                               \
      az = fmaf(wz, hc, az);                                               \
      AN = fmaf(wn, hc, AN);                                               \
    }                                                                      \
  }

  float xcur = xs[j];  // t = 0
  for (int t = 0; t < T; ++t) {
    float xnext = (t + 1 < T) ? xs[(size_t)(t + 1) * 64 + j] : 0.0f;
    lds[XB + j] = xcur;  // wave-private; ordered by lgkmcnt

    float ar = 0.f, az = 0.f, anx = 0.f, anh = 0.f;
#pragma unroll
    for (int kq = 0; kq < 16; ++kq) A_QUAD(kq * 4, kq * 4, anx);        // input
#pragma unroll
    for (int kq = 0; kq < 16; ++kq) A_QUAD(64 + kq * 4, 64 + kq * 4, anh);  // rec

    float r = sigm(ar + br);
    float z = sigm(az + bz);
    float n = tanh_f(anx + bxn + r * (anh + bhn));
    float h = (1.0f - z) * n + z * hr;
    hr = h;
    lds[XB + 64 + j] = h;
    rout[((size_t)seq * T + t) * 64 + j] = h;
    xcur = xnext;
  }
#undef A_QUAD
}

// ---------------------------------------------------------------------------
// Weight interleave prep: W3[k][j*3+g] = (k<I ? Wih[g*64+j][k] : Whh[g*64+j][k-I])
// ---------------------------------------------------------------------------
__global__ void w3_prep(const float* __restrict__ Wih0, const float* __restrict__ Whh0,
                        const float* __restrict__ Wih1, const float* __restrict__ Whh1,
                        const float* __restrict__ aWih0, const float* __restrict__ aWhh0,
                        const float* __restrict__ aWih1, const float* __restrict__ aWhh1,
                        float* __restrict__ d_e0, float* __restrict__ d_e1,
                        float* __restrict__ d_a0, float* __restrict__ d_a1) {
  const int sec = blockIdx.x >> 3;
  const int bi = blockIdx.x & 7;
  const float* Wih; const float* Whh; float* dst; int I;
  if (sec == 0)      { Wih = Wih0;  Whh = Whh0;  dst = d_e0; I = 6; }
  else if (sec == 1) { Wih = Wih1;  Whh = Whh1;  dst = d_e1; I = 64; }
  else if (sec == 2) { Wih = aWih0; Whh = aWhh0; dst = d_a0; I = 64; }
  else               { Wih = aWih1; Whh = aWhh1; dst = d_a1; I = 64; }
  const int tot = (I + 64) * 192;
  for (int idx = bi * blockDim.x + threadIdx.x; idx < tot; idx += 8 * blockDim.x) {
    const int k = idx / 192;
    const int rem = idx - k * 192;
    const int j = rem / 3;
    const int g = rem - j * 3;
    const float v = (k < I) ? Wih[(g * 64 + j) * I + k] : Whh[(g * 64 + j) * 64 + (k - I)];
    dst[idx] = v;
  }
}

// ---------------------------------------------------------------------------
// GAT algebraic prep
// ---------------------------------------------------------------------------
__global__ void gat_prep(const float* __restrict__ tW, const float* __restrict__ tb,
                         const float* __restrict__ a, float* __restrict__ vbuf) {
  const int d = threadIdx.x;  // 64 threads
  float vd = 0.0f, vs = 0.0f;
  for (int e = 0; e < 64; ++e) {
    float w = tW[e * 64 + d];
    vd = fmaf(w, a[e], vd);
    vs = fmaf(w, a[64 + e], vs);
  }
  vbuf[d] = vd;
  vbuf[64 + d] = vs;
  if (d == 0) {
    float cd = 0.0f, cs = 0.0f;
    for (int e = 0; e < 64; ++e) {
      cd = fmaf(tb[e], a[e], cd);
      cs = fmaf(tb[e], a[64 + e], cs);
    }
    vbuf[128] = cd;
    vbuf[129] = cs;
  }
}

__global__ void gat_svals(const float* __restrict__ h_enc, const float* __restrict__ vbuf,
                          float* __restrict__ s_src, float* __restrict__ s_dst) {
  const int wave = (blockIdx.x * blockDim.x + threadIdx.x) >> 6;
  const int lane = threadIdx.x & 63;
  float h = h_enc[(size_t)wave * 64 + lane];
  float pd = h * vbuf[lane];
  float ps = h * vbuf[64 + lane];
  pd = wave_sum(pd);
  ps = wave_sum(ps);
  if (lane == 0) {
    s_dst[wave] = pd + vbuf[128];
    s_src[wave] = ps + vbuf[129];
  }
}

// ---------------------------------------------------------------------------
// Dense all-pairs attention per group k (m=512)
// ---------------------------------------------------------------------------
__launch_bounds__(256)
__global__ void gat_attn(const float* __restrict__ h_enc,
                         const float* __restrict__ s_src,
                         const float* __restrict__ s_dst,
                         float* __restrict__ hout) {
  const int k = blockIdx.x >> 7;
  const int tile = blockIdx.x & 127;
  const int wv = threadIdx.x >> 6;
  const int lane = threadIdx.x & 63;
  const int i = tile * 4 + wv;
  __shared__ float sdbuf[512];
  __shared__ __align__(16) float pbuf[4][512];

  for (int u = threadIdx.x; u < 512; u += 256) sdbuf[u] = s_dst[k * 512 + u];
  __syncthreads();

  const float si = s_src[k * 512 + i];
  float ev[8];
  float mx = -1e30f;
#pragma unroll
  for (int u = 0; u < 8; ++u) {
    ev[u] = lrelu(si + sdbuf[lane + u * 64]);
    mx = fmaxf(mx, ev[u]);
  }
  mx = wave_max(mx);
  float lsum = 0.0f;
#pragma unroll
  for (int u = 0; u < 8; ++u) {
    float p = __expf(ev[u] - mx);
    pbuf[wv][lane + u * 64] = p;
    lsum += p;
  }
  lsum = wave_sum(lsum);
  const float inv = fast_rcp(lsum);

  const float* hk = h_enc + (size_t)k * 512 * 64;
  const float4* pv = (const float4*)pbuf[wv];
  float acc0 = 0.0f, acc1 = 0.0f;
#pragma unroll 2
  for (int jj = 0; jj < 128; ++jj) {
    float4 p = pv[jj];
    const float* hp = hk + (size_t)(jj * 4) * 64 + lane;
    acc0 = fmaf(p.x, hp[0], acc0);
    acc1 = fmaf(p.y, hp[64], acc1);
    acc0 = fmaf(p.z, hp[128], acc0);
    acc1 = fmaf(p.w, hp[192], acc1);
  }
  hout[((size_t)k * 512 + i) * 64 + lane] =
      (acc0 + acc1) * inv + hk[(size_t)i * 64 + lane];
}

// ---------------------------------------------------------------------------
// Post-GAT transform + pred head + ALSTM input transform
// ---------------------------------------------------------------------------
__launch_bounds__(256)
__global__ void gat_out(const float* __restrict__ hin,
                        const float* __restrict__ fcW, const float* __restrict__ fcb,
                        const float* __restrict__ fcoW, const float* __restrict__ fcob,
                        const float* __restrict__ alinW, const float* __restrict__ alinb,
                        float* __restrict__ zout, float* __restrict__ pred) {
  const int wv = threadIdx.x >> 6;
  const int lane = threadIdx.x & 63;
  const int n = blockIdx.x * 4 + wv;  // [0,10240)
  const int k = n >> 9;
  const int i = n & 511;
  __shared__ __align__(16) float rbuf[4][64];
  __shared__ __align__(16) float rbuf2[4][64];

  float4 fw[16], aw[16];
  {
    const float4* p1 = (const float4*)(fcW + lane * 64);
    const float4* p2 = (const float4*)(alinW + lane * 64);
#pragma unroll
    for (int kk = 0; kk < 16; ++kk) fw[kk] = p1[kk];
#pragma unroll
    for (int kk = 0; kk < 16; ++kk) aw[kk] = p2[kk];
  }

  rbuf[wv][lane] = hin[(size_t)n * 64 + lane];
  float h2 = fcb[lane];
  const float4* rv = (const float4*)rbuf[wv];
#pragma unroll
  for (int kk = 0; kk < 16; ++kk) h2 = dot4(fw[kk], rv[kk], h2);

  if (k == 19) {
    float pv = lrelu(h2) * fcoW[lane];
    pv = wave_sum(pv);
    if (lane == 0) pred[i] = pv + fcob[0];
  }

  rbuf2[wv][lane] = h2;
  float zz = alinb[lane];
  const float4* rv2 = (const float4*)rbuf2[wv];
#pragma unroll
  for (int kk = 0; kk < 16; ++kk) zz = dot4(aw[kk], rv2[kk], zz);
  zout[((size_t)i * 20 + k) * 64 + lane] = tanh_f(zz);
}

// ---------------------------------------------------------------------------
// ALSTM attention head
// ---------------------------------------------------------------------------
__launch_bounds__(256)
__global__ void alstm_head(const float* __restrict__ r1,  // [512][20][64]
                           const float* __restrict__ W1,  // [32][64]
                           const float* __restrict__ b1,  // [32]
                           const float* __restrict__ W2,  // [32]
                           const float* __restrict__ Wo,  // [128]
                           const float* __restrict__ bo,  // [1]
                           float* __restrict__ alstm_out) {
  const int wv = threadIdx.x >> 6;
  const int lane = threadIdx.x & 63;
  const int i = blockIdx.x * 4 + wv;  // [0,512)
  const int e = lane & 31;
  __shared__ __align__(16) float rbuf[4][64];
  __shared__ float scb[4][20];

  float4 w1r[16];
  {
    const float4* p = (const float4*)(W1 + e * 64);
#pragma unroll
    for (int kk = 0; kk < 16; ++kk) w1r[kk] = p[kk];
  }
  const float b1e = b1[e];
  const float w2e = W2[e];

  for (int k = 0; k < 20; ++k) {
    rbuf[wv][lane] = r1[((size_t)i * 20 + k) * 64 + lane];
    float u = b1e;
    const float4* rp = (const float4*)rbuf[wv];
#pragma unroll
    for (int kk = 0; kk < 16; ++kk) u = dot4(w1r[kk], rp[kk], u);
    u = tanh_f(u) * w2e;
#pragma unroll
    for (int m = 16; m; m >>= 1) u += __shfl_xor(u, m);
    if (lane == 0) scb[wv][k] = u;
  }

  float mx = -1e30f;
#pragma unroll
  for (int k = 0; k < 20; ++k) mx = fmaxf(mx, scb[wv][k]);
  float p[20];
  float l = 0.0f;
#pragma unroll
  for (int k = 0; k < 20; ++k) {
    p[k] = __expf(scb[wv][k] - mx);
    l += p[k];
  }
  const float inv = fast_rcp(l);

  float oa = 0.0f, rlast = 0.0f;
#pragma unroll
  for (int k = 0; k < 20; ++k) {
    float rv = r1[((size_t)i * 20 + k) * 64 + lane];
    oa = fmaf(p[k], rv, oa);
    if (k == 19) rlast = rv;
  }
  oa *= inv;
  float v = fmaf(Wo[lane], rlast, Wo[64 + lane] * oa);
  v = wave_sum(v);
  if (lane == 0) alstm_out[i] = v + bo[0];
}

// ---------------------------------------------------------------------------
extern "C" void kernel_launch(void* const* d_in, const int* in_sizes, int n_in,
                              void* d_out, int out_size, void* d_ws, size_t ws_size,
                              hipStream_t stream) {
  const float* x      = (const float*)d_in[0];
  const float* Wih0   = (const float*)d_in[1];
  const float* Whh0   = (const float*)d_in[2];
  const float* bih0   = (const float*)d_in[3];
  const float* bhh0   = (const float*)d_in[4];
  const float* Wih1   = (const float*)d_in[5];
  const float* Whh1   = (const float*)d_in[6];
  const float* bih1   = (const float*)d_in[7];
  const float* bhh1   = (const float*)d_in[8];
  const float* transW = (const float*)d_in[9];
  const float* transb = (const float*)d_in[10];
  const float* a_vec  = (const float*)d_in[11];
  const float* fcW    = (const float*)d_in[12];
  const float* fcb    = (const float*)d_in[13];
  const float* fcoW   = (const float*)d_in[14];
  const float* fcob   = (const float*)d_in[15];
  const float* alinW  = (const float*)d_in[16];
  const float* alinb  = (const float*)d_in[17];
  const float* aWih0  = (const float*)d_in[18];
  const float* aWhh0  = (const float*)d_in[19];
  const float* abih0  = (const float*)d_in[20];
  const float* abhh0  = (const float*)d_in[21];
  const float* aWih1  = (const float*)d_in[22];
  const float* aWhh1  = (const float*)d_in[23];
  const float* abih1  = (const float*)d_in[24];
  const float* abhh1  = (const float*)d_in[25];
  const float* att1W  = (const float*)d_in[26];
  const float* att1b  = (const float*)d_in[27];
  const float* att2W  = (const float*)d_in[28];
  const float* aloutW = (const float*)d_in[29];
  const float* aloutb = (const float*)d_in[30];

  float* out = (float*)d_out;  // [0:512) alstm_out, [512:1024) pred

  float* W = (float*)d_ws;
  float* h_enc = W; W += 10240 * 64;      // reused as r0 (steps 7-8)
  float* vbuf  = W; W += 256;
  float* s_src = W; W += 10240;
  float* s_dst = W; W += 10240;
  float* hout  = W; W += 10240 * 64;
  float* zbuf  = W; W += 512 * 20 * 64;
  float* r1    = W; W += 512 * 20 * 64;
  float* w3a0  = W; W += 24576;
  float* w3a1  = W; W += 24576;
  // time-disjoint aliases: w3e* in zbuf region (consumed at step 2, zbuf
  // written at step 6); r0 in h_enc region (h_enc last read at step 5).
  float* w3e0 = zbuf;
  float* w3e1 = zbuf + 70 * 192;

  static bool attr_done = false;
  if (!attr_done) {
    hipFuncSetAttribute((const void*)gru2_enc,
                        hipFuncAttributeMaxDynamicSharedMemorySize, E_LDS);
    hipFuncSetAttribute((const void*)gru1,
                        hipFuncAttributeMaxDynamicSharedMemorySize, A_LDS);
    attr_done = true;
  }

  // 1) weight interleave prep (all 4 GRU layers)
  w3_prep<<<32, 256, 0, stream>>>(Wih0, Whh0, Wih1, Whh1, aWih0, aWhh0,
                                  aWih1, aWhh1, w3e0, w3e1, w3a0, w3a1);
  // 2) fused 2-layer persistent GRU encoder: 256 blocks x 10 waves x SPW=4
  //    = 10240 seqs in ONE balanced round
  gru2_enc<<<256, 640, E_LDS, stream>>>(x, w3e0, w3e1, bih0, bhh0, bih1,
                                        bhh1, h_enc);
  // 3) GAT score-vector prep
  gat_prep<<<1, 64, 0, stream>>>(transW, transb, a_vec, vbuf);
  // 4) per-row s_src/s_dst
  gat_svals<<<2560, 256, 0, stream>>>(h_enc, vbuf, s_src, s_dst);
  // 5) dense attention + residual
  gat_attn<<<2560, 256, 0, stream>>>(h_enc, s_src, s_dst, hout);
  // 6) fc + pred head + ALSTM input transform (z in [i][k][64])
  gat_out<<<2560, 256, 0, stream>>>(hout, fcW, fcb, fcoW, fcob, alinW, alinb,
                                    zbuf, out + 512);
  // 7) ALSTM GRU layer 0: z -> r0 (reuses h_enc storage)
  gru1<<<64, 512, A_LDS, stream>>>(zbuf, w3a0, abih0, abhh0, 20, h_enc);
  // 8) ALSTM GRU layer 1: r0 -> r1
  gru1<<<64, 512, A_LDS, stream>>>(h_enc, w3a1, abih1, abhh1, 20, r1);
  // 9) ALSTM attention head -> alstm_out
  alstm_head<<<128, 256, 0, stream>>>(r1, att1W, att1b, att2W, aloutW, aloutb,
                                      out);
}